// Round 3
// baseline (671.029 us; speedup 1.0000x reference)
//
#include <hip/hip_runtime.h>

typedef unsigned short u16;
typedef __attribute__((ext_vector_type(8))) short short8;
typedef __attribute__((ext_vector_type(4))) float f32x4;

__device__ __forceinline__ u16 f2bf(float f){
  unsigned u = __builtin_bit_cast(unsigned, f);
  u += 0x7fffu + ((u >> 16) & 1u);
  return (u16)(u >> 16);
}

#define GLD16(gp, lp) __builtin_amdgcn_global_load_lds(                         \
    (const __attribute__((address_space(1))) void*)(gp),                        \
    (__attribute__((address_space(3))) void*)(lp), 16, 0, 0)

__device__ __forceinline__ short8 dsr128(const u16* p){
  const __attribute__((address_space(3))) u16* lp =
      (const __attribute__((address_space(3))) u16*)p;
  f32x4 r;
  asm volatile("ds_read_b128 %0, %1" : "=v"(r) : "v"(lp));
  return __builtin_bit_cast(short8, r);
}

// ---------------- cast fp32 -> bf16, 8 elems/thread ----------------
__global__ __launch_bounds__(256) void cast_bf16(const float* __restrict__ in,
                                                 u16* __restrict__ out, int n8){
  int i = blockIdx.x * blockDim.x + threadIdx.x;
  if (i >= n8) return;
  const f32x4* p = (const f32x4*)in + (size_t)i * 2;
  f32x4 a = p[0], b = p[1];
  short8 o;
  o[0]=f2bf(a[0]); o[1]=f2bf(a[1]); o[2]=f2bf(a[2]); o[3]=f2bf(a[3]);
  o[4]=f2bf(b[0]); o[5]=f2bf(b[1]); o[6]=f2bf(b[2]); o[7]=f2bf(b[3]);
  *(short8*)(out + (size_t)i * 8) = o;
}

__device__ __forceinline__ void store_val(float* p, float v){ *p = v; }
__device__ __forceinline__ void store_val(u16* p, float v){ *p = f2bf(v); }

// ---------------- 128x128 GEMM  C[M,N] = A[M,K] @ B[N,K]^T + bias ----------------
template<typename OutT, bool RELU>
__global__ __launch_bounds__(256) void gemm_bt(
    const u16* __restrict__ A, const u16* __restrict__ B,
    const float* __restrict__ bias, OutT* __restrict__ C,
    int M, int N, int K)
{
  __shared__ __align__(16) u16 a_lds[2][128*32];
  __shared__ __align__(16) u16 b_lds[2][128*32];
  const int t = threadIdx.x, w = t >> 6, l = t & 63;
  int nwg = gridDim.x * gridDim.y;
  int wg  = blockIdx.y * gridDim.x + blockIdx.x;
  int cpx = nwg >> 3;
  int swz = (wg & 7) * cpx + (wg >> 3);
  const int m0 = (swz / gridDim.x) * 128, n0 = (swz % gridDim.x) * 128;
  const int wr = (w >> 1) * 64, wc = (w & 1) * 64;

  auto stage = [&](int buf, int kt){
    const int k0 = kt * 32;
    #pragma unroll
    for (int i = 0; i < 2; ++i){
      int s = w * 2 + i;
      const u16* ga = A + (size_t)(m0 + s*16 + (l>>2)) * K + k0 + (l&3)*8;
      GLD16(ga, &a_lds[buf][s*512]);
      const u16* gb = B + (size_t)(n0 + s*16 + (l>>2)) * K + k0 + (l&3)*8;
      GLD16(gb, &b_lds[buf][s*512]);
    }
  };

  f32x4 acc[4][4];
  #pragma unroll
  for (int m=0;m<4;++m)
    #pragma unroll
    for (int n=0;n<4;++n) acc[m][n] = (f32x4){0.f,0.f,0.f,0.f};

  stage(0, 0);
  __syncthreads();
  const int nk = K / 32;
  int cur = 0;
  for (int kt = 0; kt < nk; ++kt){
    if (kt + 1 < nk) stage(cur ^ 1, kt + 1);
    short8 af[4], bfr[4];
    #pragma unroll
    for (int m=0;m<4;++m)
      af[m] = *(const short8*)&a_lds[cur][(wr + m*16 + (l&15))*32 + (l>>4)*8];
    #pragma unroll
    for (int n=0;n<4;++n)
      bfr[n] = *(const short8*)&b_lds[cur][(wc + n*16 + (l&15))*32 + (l>>4)*8];
    #pragma unroll
    for (int m=0;m<4;++m)
      #pragma unroll
      for (int n=0;n<4;++n)
        acc[m][n] = __builtin_amdgcn_mfma_f32_16x16x32_bf16(af[m], bfr[n], acc[m][n], 0, 0, 0);
    __syncthreads();
    cur ^= 1;
  }

  #pragma unroll
  for (int n=0;n<4;++n){
    int c = n0 + wc + n*16 + (l & 15);
    float bv = bias ? bias[c] : 0.f;
    #pragma unroll
    for (int m=0;m<4;++m){
      int rbase = m0 + wr + m*16 + (l >> 4) * 4;
      #pragma unroll
      for (int j=0;j<4;++j){
        float v = acc[m][n][j] + bv;
        if (RELU) v = fmaxf(v, 0.f);
        store_val(&C[(size_t)(rbase + j) * N + c], v);
      }
    }
  }
}

// ---------------- 256x256 8-phase GEMM (BK=64, 8 waves, counted vmcnt) ----------------
template<typename OutT, bool RELU>
__global__ __launch_bounds__(512, 2) void gemm256(
    const u16* __restrict__ A, const u16* __restrict__ B,
    const float* __restrict__ bias, OutT* __restrict__ C,
    int M, int N, int K)
{
  __shared__ __align__(16) u16 lds[2][2][2][16][512];   // [op][buf][kk][fr][slice] = 128 KiB
  const int t = threadIdx.x, w = t >> 6, l = t & 63;
  const int wm = w >> 2, wn = w & 3;
  int nwg = gridDim.x * gridDim.y;
  int wg  = blockIdx.y * gridDim.x + blockIdx.x;
  int cpx = nwg >> 3;
  int swz = (wg & 7) * cpx + (wg >> 3);
  const int m0 = (swz / gridDim.x) * 256, n0 = (swz % gridDim.x) * 256;
  const int nk = K >> 6;

  auto stage_slot = [&](int s){
    if (s >= 4*nk) return;
    int u = s >> 2, h = s & 3;
    int buf = u & 1, kk = h >> 1, op = h & 1;
    int k0 = u*64 + kk*32 + (l>>4)*8;
    if (op == 0){
      #pragma unroll
      for (int i2=0;i2<2;++i2){
        int fr = 2*w + i2;
        const u16* g = A + (size_t)(m0 + fr*16 + (l&15)) * K + k0;
        GLD16(g, &lds[0][buf][kk][fr][0]);
      }
    } else {
      #pragma unroll
      for (int i2=0;i2<2;++i2){
        int fr = 2*w + i2;
        const u16* g = B + (size_t)(n0 + fr*16 + (l&15)) * K + k0;
        GLD16(g, &lds[1][buf][kk][fr][0]);
      }
    }
  };

  f32x4 acc[8][4];
  #pragma unroll
  for (int m=0;m<8;++m)
    #pragma unroll
    for (int n=0;n<4;++n) acc[m][n] = (f32x4){0.f,0.f,0.f,0.f};

  #pragma unroll
  for (int s=0;s<6;++s) stage_slot(s);
  asm volatile("s_waitcnt vmcnt(4)" ::: "memory");
  asm volatile("s_barrier" ::: "memory");

  short8 af[4], bfr[4];
  auto phase = [&](int buf, int kk, int mh, int slot, bool gate){
    if (mh == 0){
      #pragma unroll
      for (int n=0;n<4;++n) bfr[n] = dsr128(&lds[1][buf][kk][wn*4+n][l*8]);
    }
    #pragma unroll
    for (int mi=0;mi<4;++mi) af[mi] = dsr128(&lds[0][buf][kk][wm*8+mh*4+mi][l*8]);
    stage_slot(slot);
    if (gate) asm volatile("s_waitcnt vmcnt(6)" ::: "memory");
    asm volatile("s_barrier" ::: "memory");
    asm volatile("s_waitcnt lgkmcnt(0)" ::: "memory");
    __builtin_amdgcn_sched_barrier(0);
    __builtin_amdgcn_s_setprio(1);
    #pragma unroll
    for (int mi=0;mi<4;++mi)
      #pragma unroll
      for (int n=0;n<4;++n)
        acc[mh*4+mi][n] = __builtin_amdgcn_mfma_f32_16x16x32_bf16(
            af[mi], bfr[n], acc[mh*4+mi][n], 0, 0, 0);
    __builtin_amdgcn_s_setprio(0);
    asm volatile("s_barrier" ::: "memory");
  };

  const int nkh = nk >> 1;
  for (int i = 0; i < nkh; ++i){
    int s0 = 8*i;
    phase(0,0,0, s0+6,  false);
    phase(0,0,1, s0+7,  true );
    phase(0,1,0, s0+8,  false);
    phase(0,1,1, s0+9,  true );
    phase(1,0,0, s0+10, false);
    phase(1,0,1, s0+11, true );
    phase(1,1,0, s0+12, false);
    phase(1,1,1, s0+13, true );
  }
  asm volatile("s_waitcnt vmcnt(0)" ::: "memory");

  #pragma unroll
  for (int n=0;n<4;++n){
    int c = n0 + wn*64 + n*16 + (l & 15);
    float bv = bias ? bias[c] : 0.f;
    #pragma unroll
    for (int am=0;am<8;++am){
      int rbase = m0 + wm*128 + am*16 + (l >> 4) * 4;
      #pragma unroll
      for (int j=0;j<4;++j){
        float v = acc[am][n][j] + bv;
        if (RELU) v = fmaxf(v, 0.f);
        store_val(&C[(size_t)(rbase + j) * N + c], v);
      }
    }
  }
}

// ---------------- fused attention: online stats + recompute + PV ----------------
__global__ __launch_bounds__(256) void attn_fused(
    const u16* __restrict__ qkv, float* __restrict__ attn,
    const float* __restrict__ head_mask, u16* __restrict__ attn_out)
{
  __shared__ __align__(16) u16 qs[64*64];
  __shared__ __align__(16) u16 ks[2][64*64];
  __shared__ __align__(16) u16 vt[64*72];
  __shared__ __align__(16) u16 pl[64*72];
  const int t = threadIdx.x, w = t >> 6, l = t & 63;
  const int bh = blockIdx.y, b = bh >> 4, h = bh & 15;
  const int q0 = blockIdx.x * 64;
  const size_t qbase = (size_t)b * 1024 * 3072;
  const float hm = head_mask[0];

  auto stageQ = [&](){
    #pragma unroll
    for (int i=0;i<2;++i){
      int s = w*2 + i;
      int row = s*8 + (l>>3);
      int gcol = (8*(l&7) - 16*(row&3)) & 63;
      const u16* g = qkv + qbase + (size_t)(q0 + row) * 3072 + h*64 + gcol;
      GLD16(g, &qs[s*512]);
    }
  };
  auto stageK = [&](int buf, int ct){
    #pragma unroll
    for (int i=0;i<2;++i){
      int s = w*2 + i;
      int row = s*8 + (l>>3);
      int gcol = (8*(l&7) - 16*(row&3)) & 63;
      const u16* g = qkv + qbase + (size_t)(ct*64 + row) * 3072 + 1024 + h*64 + gcol;
      GLD16(g, &ks[buf][s*512]);
    }
  };

  stageQ();
  stageK(0, 0);
  __syncthreads();

  const int rq = w*16 + (l&15);
  const int qrot = 16*(rq&3);
  short8 a0 = *(const short8*)&qs[rq*64 + (((l>>4)*8      + qrot) & 63)];
  short8 a1 = *(const short8*)&qs[rq*64 + (((l>>4)*8 + 32 + qrot) & 63)];

  auto qkmma = [&](int buf, f32x4* acc){
    #pragma unroll
    for (int n=0;n<4;++n){
      int r = n*16 + (l&15);
      int rot = 16*(r&3);
      short8 b0 = *(const short8*)&ks[buf][r*64 + (((l>>4)*8      + rot) & 63)];
      acc[n] = __builtin_amdgcn_mfma_f32_16x16x32_bf16(a0, b0, acc[n], 0, 0, 0);
    }
    #pragma unroll
    for (int n=0;n<4;++n){
      int r = n*16 + (l&15);
      int rot = 16*(r&3);
      short8 b1 = *(const short8*)&ks[buf][r*64 + (((l>>4)*8 + 32 + rot) & 63)];
      acc[n] = __builtin_amdgcn_mfma_f32_16x16x32_bf16(a1, b1, acc[n], 0, 0, 0);
    }
  };

  float m_run[4] = {-1e30f,-1e30f,-1e30f,-1e30f};
  float l_run[4] = {0.f,0.f,0.f,0.f};
  int cur = 0;
  for (int ct = 0; ct < 16; ++ct){
    if (ct < 15) stageK(cur ^ 1, ct + 1);
    f32x4 acc[4];
    #pragma unroll
    for (int n=0;n<4;++n) acc[n] = (f32x4){0.f,0.f,0.f,0.f};
    qkmma(cur, acc);
    #pragma unroll
    for (int j=0;j<4;++j){
      float s0 = acc[0][j]*0.125f, s1 = acc[1][j]*0.125f;
      float s2 = acc[2][j]*0.125f, s3 = acc[3][j]*0.125f;
      float mx = fmaxf(fmaxf(s0,s1), fmaxf(s2,s3));
      #pragma unroll
      for (int o=1;o<16;o<<=1) mx = fmaxf(mx, __shfl_xor(mx, o));
      float mn = fmaxf(m_run[j], mx);
      float es = __expf(s0-mn) + __expf(s1-mn) + __expf(s2-mn) + __expf(s3-mn);
      #pragma unroll
      for (int o=1;o<16;o<<=1) es += __shfl_xor(es, o);
      l_run[j] = l_run[j] * __expf(m_run[j] - mn) + es;
      m_run[j] = mn;
    }
    __syncthreads();
    cur ^= 1;
  }

  float rcp[4];
  #pragma unroll
  for (int j=0;j<4;++j) rcp[j] = hm / l_run[j];

  float* attn_b = attn + (size_t)bh * 1024 * 1024;
  const int kv = t & 31, u = t >> 5;
  f32x4 accO[4];
  #pragma unroll
  for (int n=0;n<4;++n) accO[n] = (f32x4){0.f,0.f,0.f,0.f};

  stageK(0, 0);
  for (int ct = 0; ct < 16; ++ct){
    const u16* g0 = qkv + qbase + (size_t)(ct*64 + 2*kv) * 3072 + 2048 + h*64 + u*8;
    short8 v0 = *(const short8*)g0;
    short8 v1 = *(const short8*)(g0 + 3072);

    __syncthreads();
    if (ct < 15) stageK(cur ^ 1, ct + 1);

    f32x4 acc2[4];
    #pragma unroll
    for (int n=0;n<4;++n) acc2[n] = (f32x4){0.f,0.f,0.f,0.f};
    qkmma(cur, acc2);

    #pragma unroll
    for (int j=0;j<4;++j){
      int rloc = w*16 + (l>>4)*4 + j;
      float p0 = __expf(acc2[0][j]*0.125f - m_run[j]) * rcp[j];
      float p1 = __expf(acc2[1][j]*0.125f - m_run[j]) * rcp[j];
      float p2 = __expf(acc2[2][j]*0.125f - m_run[j]) * rcp[j];
      float p3 = __expf(acc2[3][j]*0.125f - m_run[j]) * rcp[j];
      float* ap = attn_b + (size_t)(q0 + rloc) * 1024 + ct*64 + (l&15);
      ap[0] = p0; ap[16] = p1; ap[32] = p2; ap[48] = p3;
      u16* pp = &pl[rloc*72 + (l&15)];
      pp[0] = f2bf(p0); pp[16] = f2bf(p1); pp[32] = f2bf(p2); pp[48] = f2bf(p3);
    }
    #pragma unroll
    for (int i=0;i<8;++i){
      unsigned wrd = (unsigned)(u16)v0[i] | ((unsigned)(u16)v1[i] << 16);
      *(unsigned*)&vt[(u*8 + i)*72 + 2*kv] = wrd;
    }
    __syncthreads();
    #pragma unroll
    for (int kk=0;kk<2;++kk){
      short8 pa = *(const short8*)&pl[(w*16 + (l&15))*72 + kk*32 + (l>>4)*8];
      #pragma unroll
      for (int n=0;n<4;++n){
        short8 vf = *(const short8*)&vt[(n*16 + (l&15))*72 + kk*32 + (l>>4)*8];
        accO[n] = __builtin_amdgcn_mfma_f32_16x16x32_bf16(pa, vf, accO[n], 0, 0, 0);
      }
    }
    cur ^= 1;
  }

  #pragma unroll
  for (int n=0;n<4;++n){
    int col = h*64 + n*16 + (l & 15);
    #pragma unroll
    for (int j=0;j<4;++j){
      int row = q0 + w*16 + (l>>4)*4 + j;
      attn_out[(size_t)(b*1024 + row) * 1024 + col] = f2bf(accO[n][j]);
    }
  }
}

// ---------------- fused residual + LayerNorm ----------------
__global__ __launch_bounds__(256) void ln_kernel(
    const float* __restrict__ a, const float* __restrict__ r,
    const float* __restrict__ w, const float* __restrict__ b,
    float* __restrict__ outf, u16* __restrict__ outb)
{
  const int row = blockIdx.x, t = threadIdx.x;
  const size_t base = (size_t)row * 1024;
  float v[4];
  float s1 = 0.f, s2 = 0.f;
  #pragma unroll
  for (int i=0;i<4;++i){
    int c = i*256 + t;
    float x = a[base + c] + r[base + c];
    v[i] = x; s1 += x; s2 += x * x;
  }
  #pragma unroll
  for (int o=32;o;o>>=1){ s1 += __shfl_xor(s1, o); s2 += __shfl_xor(s2, o); }
  __shared__ float red[8];
  int wv = t >> 6, l = t & 63;
  if (l == 0){ red[wv] = s1; red[4+wv] = s2; }
  __syncthreads();
  s1 = red[0]+red[1]+red[2]+red[3];
  s2 = red[4]+red[5]+red[6]+red[7];
  float mu  = s1 * (1.f/1024.f);
  float var = s2 * (1.f/1024.f) - mu*mu;
  float rstd = rsqrtf(var + 1e-5f);
  #pragma unroll
  for (int i=0;i<4;++i){
    int c = i*256 + t;
    float y = (v[i]-mu)*rstd*w[c] + b[c];
    if (outf) outf[base + c] = y;
    if (outb) outb[base + c] = f2bf(y);
  }
}

// ---------------- launch ----------------
extern "C" void kernel_launch(void* const* d_in, const int* in_sizes, int n_in,
                              void* d_out, int out_size, void* d_ws, size_t ws_size,
                              hipStream_t stream)
{
  const float* x          = (const float*)d_in[0];
  const float* in_proj_w  = (const float*)d_in[1];
  const float* in_proj_b  = (const float*)d_in[2];
  const float* out_proj_w = (const float*)d_in[3];
  const float* out_proj_b = (const float*)d_in[4];
  const float* ln1_w = (const float*)d_in[5];
  const float* ln1_b = (const float*)d_in[6];
  const float* ln2_w = (const float*)d_in[7];
  const float* ln2_b = (const float*)d_in[8];
  const float* ffn_w1 = (const float*)d_in[9];
  const float* ffn_b1 = (const float*)d_in[10];
  const float* ffn_w2 = (const float*)d_in[11];
  const float* ffn_b2 = (const float*)d_in[12];
  const float* head_mask = (const float*)d_in[13];

  const int B = 8, S = 1024, D = 1024, DFF = 4096;
  const int M = B * S;

  char* ws = (char*)d_ws;
  u16*   qkv_bf = (u16*)ws;                              // 50331648 B
  char*  r1 = ws + 50331648;
  u16*   x_bf    = (u16*)r1;                             // 16777216
  u16*   wqkv_bf = (u16*)(r1 + 16777216);                // 6291456
  u16*   w1_bf   = (u16*)r1;                             // 8388608 (reuse after QKV gemm)
  u16*   w2_bf   = (u16*)(r1 + 8388608);                 // 8388608
  u16*   wout_bf = (u16*)(r1 + 16777216);                // 2097152
  char*  p2 = ws + 50331648 + 23068672;
  u16*   attn_out_bf = (u16*)(p2 + 1048576);             // 16777216 (later x1_bf)
  u16*   x1_bf = attn_out_bf;
  float* proj = (float*)(p2 + 1048576 + 16777216);       // 33554432 (later ff)
  float* ff = proj;
  float* x1 = (float*)((char*)proj + 33554432);          // 33554432
  u16*   h_bf = (u16*)((char*)x1 + 33554432);            // 67108864

  float* out  = (float*)d_out;
  float* attn = out + 8388608;

  cast_bf16<<<(M*D/8 + 255)/256, 256, 0, stream>>>(x, x_bf, M*D/8);
  cast_bf16<<<(3*D*D/8 + 255)/256, 256, 0, stream>>>(in_proj_w, wqkv_bf, 3*D*D/8);

  gemm256<u16,false><<<dim3(3*D/256, M/256), 512, 0, stream>>>(x_bf, wqkv_bf, in_proj_b, qkv_bf, M, 3*D, D);

  cast_bf16<<<(D*D/8 + 255)/256, 256, 0, stream>>>(out_proj_w, wout_bf, D*D/8);
  cast_bf16<<<(DFF*D/8 + 255)/256, 256, 0, stream>>>(ffn_w1, w1_bf, DFF*D/8);
  cast_bf16<<<(D*DFF/8 + 255)/256, 256, 0, stream>>>(ffn_w2, w2_bf, D*DFF/8);

  attn_fused<<<dim3(16, 128), 256, 0, stream>>>(qkv_bf, attn, head_mask, attn_out_bf);

  gemm_bt<float,false><<<dim3(D/128, M/128), 256, 0, stream>>>(attn_out_bf, wout_bf, out_proj_b, proj, M, D, D);
  ln_kernel<<<M, 256, 0, stream>>>(proj, x, ln1_w, ln1_b, x1, x1_bf);
  gemm256<u16,true><<<dim3(DFF/256, M/256), 512, 0, stream>>>(x1_bf, w1_bf, ffn_b1, h_bf, M, DFF, D);
  gemm_bt<float,false><<<dim3(D/128, M/128), 256, 0, stream>>>(h_bf, w2_bf, ffn_b2, ff, M, D, DFF);
  ln_kernel<<<M, 256, 0, stream>>>(ff, x1, ln2_w, ln2_b, out, (u16*)nullptr);
}

// Round 4
// 632.618 us; speedup vs baseline: 1.0607x; 1.0607x over previous
//
#include <hip/hip_runtime.h>

typedef unsigned short u16;
typedef __attribute__((ext_vector_type(8))) short short8;
typedef __attribute__((ext_vector_type(4))) float f32x4;

__device__ __forceinline__ u16 f2bf(float f){
  unsigned u = __builtin_bit_cast(unsigned, f);
  u += 0x7fffu + ((u >> 16) & 1u);
  return (u16)(u >> 16);
}

#define GLD16(gp, lp) __builtin_amdgcn_global_load_lds(                         \
    (const __attribute__((address_space(1))) void*)(gp),                        \
    (__attribute__((address_space(3))) void*)(lp), 16, 0, 0)

// ---------------- cast fp32 -> bf16, 8 elems/thread ----------------
__global__ __launch_bounds__(256) void cast_bf16(const float* __restrict__ in,
                                                 u16* __restrict__ out, int n8){
  int i = blockIdx.x * blockDim.x + threadIdx.x;
  if (i >= n8) return;
  const f32x4* p = (const f32x4*)in + (size_t)i * 2;
  f32x4 a = p[0], b = p[1];
  short8 o;
  o[0]=f2bf(a[0]); o[1]=f2bf(a[1]); o[2]=f2bf(a[2]); o[3]=f2bf(a[3]);
  o[4]=f2bf(b[0]); o[5]=f2bf(b[1]); o[6]=f2bf(b[2]); o[7]=f2bf(b[3]);
  *(short8*)(out + (size_t)i * 8) = o;
}

__device__ __forceinline__ void store_val(float* p, float v){ *p = v; }
__device__ __forceinline__ void store_val(u16* p, float v){ *p = f2bf(v); }

// ---------------- 128x128 GEMM  C[M,N] = A[M,K] @ B[N,K]^T + bias ----------------
template<typename OutT, bool RELU>
__global__ __launch_bounds__(256) void gemm_bt(
    const u16* __restrict__ A, const u16* __restrict__ B,
    const float* __restrict__ bias, OutT* __restrict__ C,
    int M, int N, int K)
{
  __shared__ __align__(16) u16 a_lds[2][128*32];
  __shared__ __align__(16) u16 b_lds[2][128*32];
  const int t = threadIdx.x, w = t >> 6, l = t & 63;
  int nwg = gridDim.x * gridDim.y;
  int wg  = blockIdx.y * gridDim.x + blockIdx.x;
  int cpx = nwg >> 3;
  int swz = (wg & 7) * cpx + (wg >> 3);
  const int m0 = (swz / gridDim.x) * 128, n0 = (swz % gridDim.x) * 128;
  const int wr = (w >> 1) * 64, wc = (w & 1) * 64;

  auto stage = [&](int buf, int kt){
    const int k0 = kt * 32;
    #pragma unroll
    for (int i = 0; i < 2; ++i){
      int s = w * 2 + i;
      const u16* ga = A + (size_t)(m0 + s*16 + (l>>2)) * K + k0 + (l&3)*8;
      GLD16(ga, &a_lds[buf][s*512]);
      const u16* gb = B + (size_t)(n0 + s*16 + (l>>2)) * K + k0 + (l&3)*8;
      GLD16(gb, &b_lds[buf][s*512]);
    }
  };

  f32x4 acc[4][4];
  #pragma unroll
  for (int m=0;m<4;++m)
    #pragma unroll
    for (int n=0;n<4;++n) acc[m][n] = (f32x4){0.f,0.f,0.f,0.f};

  stage(0, 0);
  __syncthreads();
  const int nk = K / 32;
  int cur = 0;
  for (int kt = 0; kt < nk; ++kt){
    if (kt + 1 < nk) stage(cur ^ 1, kt + 1);
    short8 af[4], bfr[4];
    #pragma unroll
    for (int m=0;m<4;++m)
      af[m] = *(const short8*)&a_lds[cur][(wr + m*16 + (l&15))*32 + (l>>4)*8];
    #pragma unroll
    for (int n=0;n<4;++n)
      bfr[n] = *(const short8*)&b_lds[cur][(wc + n*16 + (l&15))*32 + (l>>4)*8];
    #pragma unroll
    for (int m=0;m<4;++m)
      #pragma unroll
      for (int n=0;n<4;++n)
        acc[m][n] = __builtin_amdgcn_mfma_f32_16x16x32_bf16(af[m], bfr[n], acc[m][n], 0, 0, 0);
    __syncthreads();
    cur ^= 1;
  }

  #pragma unroll
  for (int n=0;n<4;++n){
    int c = n0 + wc + n*16 + (l & 15);
    float bv = bias ? bias[c] : 0.f;
    #pragma unroll
    for (int m=0;m<4;++m){
      int rbase = m0 + wr + m*16 + (l >> 4) * 4;
      #pragma unroll
      for (int j=0;j<4;++j){
        float v = acc[m][n][j] + bv;
        if (RELU) v = fmaxf(v, 0.f);
        store_val(&C[(size_t)(rbase + j) * N + c], v);
      }
    }
  }
}

// ---------------- fused attention: online stats + recompute + PV ----------------
// Pass 1: QK^T tiles; PER-LANE deferred (m,l) — zero cross-lane ops in the
// ct loop; one 16-lane exp-merge combine at the end (exact softmax stats,
// reassociated fp32 only).
// Pass 2: recompute QK^T (bitwise-identical), write normalized attn,
// repack P->bf16 via LDS, PV MFMA with transposed V.
__global__ __launch_bounds__(256) void attn_fused(
    const u16* __restrict__ qkv, float* __restrict__ attn,
    const float* __restrict__ head_mask, u16* __restrict__ attn_out)
{
  __shared__ __align__(16) u16 qs[64*64];
  __shared__ __align__(16) u16 ks[2][64*64];
  __shared__ __align__(16) u16 vt[64*72];
  __shared__ __align__(16) u16 pl[64*72];
  const int t = threadIdx.x, w = t >> 6, l = t & 63;
  const int bh = blockIdx.y, b = bh >> 4, h = bh & 15;
  const int q0 = blockIdx.x * 64;
  const size_t qbase = (size_t)b * 1024 * 3072;
  const float hm = head_mask[0];

  auto stageQ = [&](){
    #pragma unroll
    for (int i=0;i<2;++i){
      int s = w*2 + i;
      int row = s*8 + (l>>3);
      int gcol = (8*(l&7) - 16*(row&3)) & 63;
      const u16* g = qkv + qbase + (size_t)(q0 + row) * 3072 + h*64 + gcol;
      GLD16(g, &qs[s*512]);
    }
  };
  auto stageK = [&](int buf, int ct){
    #pragma unroll
    for (int i=0;i<2;++i){
      int s = w*2 + i;
      int row = s*8 + (l>>3);
      int gcol = (8*(l&7) - 16*(row&3)) & 63;
      const u16* g = qkv + qbase + (size_t)(ct*64 + row) * 3072 + 1024 + h*64 + gcol;
      GLD16(g, &ks[buf][s*512]);
    }
  };

  stageQ();
  stageK(0, 0);
  __syncthreads();

  const int rq = w*16 + (l&15);
  const int qrot = 16*(rq&3);
  short8 a0 = *(const short8*)&qs[rq*64 + (((l>>4)*8      + qrot) & 63)];
  short8 a1 = *(const short8*)&qs[rq*64 + (((l>>4)*8 + 32 + qrot) & 63)];

  auto qkmma = [&](int buf, f32x4* acc){
    #pragma unroll
    for (int n=0;n<4;++n){
      int r = n*16 + (l&15);
      int rot = 16*(r&3);
      short8 b0 = *(const short8*)&ks[buf][r*64 + (((l>>4)*8      + rot) & 63)];
      acc[n] = __builtin_amdgcn_mfma_f32_16x16x32_bf16(a0, b0, acc[n], 0, 0, 0);
    }
    #pragma unroll
    for (int n=0;n<4;++n){
      int r = n*16 + (l&15);
      int rot = 16*(r&3);
      short8 b1 = *(const short8*)&ks[buf][r*64 + (((l>>4)*8 + 32 + rot) & 63)];
      acc[n] = __builtin_amdgcn_mfma_f32_16x16x32_bf16(a1, b1, acc[n], 0, 0, 0);
    }
  };

  // ---- pass 1: per-lane deferred (m,l); no cross-lane ops in the loop ----
  float m_run[4] = {-1e30f,-1e30f,-1e30f,-1e30f};
  float l_run[4] = {0.f,0.f,0.f,0.f};
  int cur = 0;
  for (int ct = 0; ct < 16; ++ct){
    if (ct < 15) stageK(cur ^ 1, ct + 1);
    f32x4 acc[4];
    #pragma unroll
    for (int n=0;n<4;++n) acc[n] = (f32x4){0.f,0.f,0.f,0.f};
    qkmma(cur, acc);
    #pragma unroll
    for (int j=0;j<4;++j){
      float s0 = acc[0][j]*0.125f, s1 = acc[1][j]*0.125f;
      float s2 = acc[2][j]*0.125f, s3 = acc[3][j]*0.125f;
      float mx = fmaxf(fmaxf(s0,s1), fmaxf(s2,s3));
      float mn = fmaxf(m_run[j], mx);
      l_run[j] = l_run[j] * __expf(m_run[j] - mn)
               + __expf(s0-mn) + __expf(s1-mn) + __expf(s2-mn) + __expf(s3-mn);
      m_run[j] = mn;
    }
    __syncthreads();
    cur ^= 1;
  }

  // ---- one-time 16-lane combine (row = lanes sharing l>>4, over l&15) ----
  float rcp[4];
  #pragma unroll
  for (int j=0;j<4;++j){
    float m = m_run[j], lv = l_run[j];
    #pragma unroll
    for (int o=1;o<16;o<<=1){
      float m2 = __shfl_xor(m, o);
      float l2 = __shfl_xor(lv, o);
      float mn = fmaxf(m, m2);
      lv = lv * __expf(m - mn) + l2 * __expf(m2 - mn);
      m = mn;
    }
    m_run[j] = m;
    rcp[j] = hm / lv;
  }

  // ---- pass 2: recompute, normalize, write attn, PV ----
  float* attn_b = attn + (size_t)bh * 1024 * 1024;
  const int kv = t & 31, u = t >> 5;
  f32x4 accO[4];
  #pragma unroll
  for (int n=0;n<4;++n) accO[n] = (f32x4){0.f,0.f,0.f,0.f};

  stageK(0, 0);
  for (int ct = 0; ct < 16; ++ct){
    const u16* g0 = qkv + qbase + (size_t)(ct*64 + 2*kv) * 3072 + 2048 + h*64 + u*8;
    short8 v0 = *(const short8*)g0;
    short8 v1 = *(const short8*)(g0 + 3072);

    __syncthreads();
    if (ct < 15) stageK(cur ^ 1, ct + 1);

    f32x4 acc2[4];
    #pragma unroll
    for (int n=0;n<4;++n) acc2[n] = (f32x4){0.f,0.f,0.f,0.f};
    qkmma(cur, acc2);

    #pragma unroll
    for (int j=0;j<4;++j){
      int rloc = w*16 + (l>>4)*4 + j;
      float p0 = __expf(acc2[0][j]*0.125f - m_run[j]) * rcp[j];
      float p1 = __expf(acc2[1][j]*0.125f - m_run[j]) * rcp[j];
      float p2 = __expf(acc2[2][j]*0.125f - m_run[j]) * rcp[j];
      float p3 = __expf(acc2[3][j]*0.125f - m_run[j]) * rcp[j];
      float* ap = attn_b + (size_t)(q0 + rloc) * 1024 + ct*64 + (l&15);
      ap[0] = p0; ap[16] = p1; ap[32] = p2; ap[48] = p3;
      u16* pp = &pl[rloc*72 + (l&15)];
      pp[0] = f2bf(p0); pp[16] = f2bf(p1); pp[32] = f2bf(p2); pp[48] = f2bf(p3);
    }
    #pragma unroll
    for (int i=0;i<8;++i){
      unsigned wrd = (unsigned)(u16)v0[i] | ((unsigned)(u16)v1[i] << 16);
      *(unsigned*)&vt[(u*8 + i)*72 + 2*kv] = wrd;
    }
    __syncthreads();
    #pragma unroll
    for (int kk=0;kk<2;++kk){
      short8 pa = *(const short8*)&pl[(w*16 + (l&15))*72 + kk*32 + (l>>4)*8];
      #pragma unroll
      for (int n=0;n<4;++n){
        short8 vf = *(const short8*)&vt[(n*16 + (l&15))*72 + kk*32 + (l>>4)*8];
        accO[n] = __builtin_amdgcn_mfma_f32_16x16x32_bf16(pa, vf, accO[n], 0, 0, 0);
      }
    }
    cur ^= 1;
  }

  #pragma unroll
  for (int n=0;n<4;++n){
    int col = h*64 + n*16 + (l & 15);
    #pragma unroll
    for (int j=0;j<4;++j){
      int row = q0 + w*16 + (l>>4)*4 + j;
      attn_out[(size_t)(b*1024 + row) * 1024 + col] = f2bf(accO[n][j]);
    }
  }
}

// ---------------- fused residual + LayerNorm ----------------
__global__ __launch_bounds__(256) void ln_kernel(
    const float* __restrict__ a, const float* __restrict__ r,
    const float* __restrict__ w, const float* __restrict__ b,
    float* __restrict__ outf, u16* __restrict__ outb)
{
  const int row = blockIdx.x, t = threadIdx.x;
  const size_t base = (size_t)row * 1024;
  float v[4];
  float s1 = 0.f, s2 = 0.f;
  #pragma unroll
  for (int i=0;i<4;++i){
    int c = i*256 + t;
    float x = a[base + c] + r[base + c];
    v[i] = x; s1 += x; s2 += x * x;
  }
  #pragma unroll
  for (int o=32;o;o>>=1){ s1 += __shfl_xor(s1, o); s2 += __shfl_xor(s2, o); }
  __shared__ float red[8];
  int wv = t >> 6, l = t & 63;
  if (l == 0){ red[wv] = s1; red[4+wv] = s2; }
  __syncthreads();
  s1 = red[0]+red[1]+red[2]+red[3];
  s2 = red[4]+red[5]+red[6]+red[7];
  float mu  = s1 * (1.f/1024.f);
  float var = s2 * (1.f/1024.f) - mu*mu;
  float rstd = rsqrtf(var + 1e-5f);
  #pragma unroll
  for (int i=0;i<4;++i){
    int c = i*256 + t;
    float y = (v[i]-mu)*rstd*w[c] + b[c];
    if (outf) outf[base + c] = y;
    if (outb) outb[base + c] = f2bf(y);
  }
}

// ---------------- launch ----------------
extern "C" void kernel_launch(void* const* d_in, const int* in_sizes, int n_in,
                              void* d_out, int out_size, void* d_ws, size_t ws_size,
                              hipStream_t stream)
{
  const float* x          = (const float*)d_in[0];
  const float* in_proj_w  = (const float*)d_in[1];
  const float* in_proj_b  = (const float*)d_in[2];
  const float* out_proj_w = (const float*)d_in[3];
  const float* out_proj_b = (const float*)d_in[4];
  const float* ln1_w = (const float*)d_in[5];
  const float* ln1_b = (const float*)d_in[6];
  const float* ln2_w = (const float*)d_in[7];
  const float* ln2_b = (const float*)d_in[8];
  const float* ffn_w1 = (const float*)d_in[9];
  const float* ffn_b1 = (const float*)d_in[10];
  const float* ffn_w2 = (const float*)d_in[11];
  const float* ffn_b2 = (const float*)d_in[12];
  const float* head_mask = (const float*)d_in[13];

  const int B = 8, S = 1024, D = 1024, DFF = 4096;
  const int M = B * S;

  char* ws = (char*)d_ws;
  u16*   qkv_bf = (u16*)ws;                              // 50331648 B
  char*  r1 = ws + 50331648;
  u16*   x_bf    = (u16*)r1;                             // 16777216
  u16*   wqkv_bf = (u16*)(r1 + 16777216);                // 6291456
  u16*   w1_bf   = (u16*)r1;                             // 8388608 (reuse after QKV gemm)
  u16*   w2_bf   = (u16*)(r1 + 8388608);                 // 8388608
  u16*   wout_bf = (u16*)(r1 + 16777216);                // 2097152
  char*  p2 = ws + 50331648 + 23068672;
  u16*   attn_out_bf = (u16*)(p2 + 1048576);             // 16777216 (later x1_bf)
  u16*   x1_bf = attn_out_bf;
  float* proj = (float*)(p2 + 1048576 + 16777216);       // 33554432 (later ff)
  float* ff = proj;
  float* x1 = (float*)((char*)proj + 33554432);          // 33554432
  u16*   h_bf = (u16*)((char*)x1 + 33554432);            // 67108864

  float* out  = (float*)d_out;
  float* attn = out + 8388608;

  cast_bf16<<<(M*D/8 + 255)/256, 256, 0, stream>>>(x, x_bf, M*D/8);
  cast_bf16<<<(3*D*D/8 + 255)/256, 256, 0, stream>>>(in_proj_w, wqkv_bf, 3*D*D/8);

  gemm_bt<u16,false><<<dim3(3*D/128, M/128), 256, 0, stream>>>(x_bf, wqkv_bf, in_proj_b, qkv_bf, M, 3*D, D);

  cast_bf16<<<(D*D/8 + 255)/256, 256, 0, stream>>>(out_proj_w, wout_bf, D*D/8);
  cast_bf16<<<(DFF*D/8 + 255)/256, 256, 0, stream>>>(ffn_w1, w1_bf, DFF*D/8);
  cast_bf16<<<(D*DFF/8 + 255)/256, 256, 0, stream>>>(ffn_w2, w2_bf, D*DFF/8);

  attn_fused<<<dim3(16, 128), 256, 0, stream>>>(qkv_bf, attn, head_mask, attn_out_bf);

  gemm_bt<float,false><<<dim3(D/128, M/128), 256, 0, stream>>>(attn_out_bf, wout_bf, out_proj_b, proj, M, D, D);
  ln_kernel<<<M, 256, 0, stream>>>(proj, x, ln1_w, ln1_b, x1, x1_bf);
  gemm_bt<u16,true><<<dim3(DFF/128, M/128), 256, 0, stream>>>(x1_bf, w1_bf, ffn_b1, h_bf, M, DFF, D);
  gemm_bt<float,false><<<dim3(D/128, M/128), 256, 0, stream>>>(h_bf, w2_bf, ffn_b2, ff, M, D, DFF);
  ln_kernel<<<M, 256, 0, stream>>>(ff, x1, ln2_w, ln2_b, out, (u16*)nullptr);
}

// Round 5
// 593.382 us; speedup vs baseline: 1.1309x; 1.0661x over previous
//
#include <hip/hip_runtime.h>

typedef unsigned short u16;
typedef __attribute__((ext_vector_type(8))) short short8;
typedef __attribute__((ext_vector_type(4))) float f32x4;

__device__ __forceinline__ u16 f2bf(float f){
  unsigned u = __builtin_bit_cast(unsigned, f);
  u += 0x7fffu + ((u >> 16) & 1u);
  return (u16)(u >> 16);
}
__device__ __forceinline__ float bf2f(u16 v){
  unsigned u = (unsigned)v << 16;
  return __builtin_bit_cast(float, u);
}

#define GLD16(gp, lp) __builtin_amdgcn_global_load_lds(                         \
    (const __attribute__((address_space(1))) void*)(gp),                        \
    (__attribute__((address_space(3))) void*)(lp), 16, 0, 0)

// ---------------- fused cast: all fp32->bf16 conversions in one kernel ----------------
__device__ __forceinline__ void cast_seg(const float* __restrict__ s,
                                         u16* __restrict__ d, int n8,
                                         int tid, int stride){
  for (int i = tid; i < n8; i += stride){
    const f32x4* p = (const f32x4*)s + (size_t)i * 2;
    f32x4 a = p[0], b = p[1];
    short8 o;
    o[0]=f2bf(a[0]); o[1]=f2bf(a[1]); o[2]=f2bf(a[2]); o[3]=f2bf(a[3]);
    o[4]=f2bf(b[0]); o[5]=f2bf(b[1]); o[6]=f2bf(b[2]); o[7]=f2bf(b[3]);
    *(short8*)(d + (size_t)i * 8) = o;
  }
}

__global__ __launch_bounds__(256) void cast_all(
    const float* s0, u16* d0, int n0,
    const float* s1, u16* d1, int n1,
    const float* s2, u16* d2, int n2,
    const float* s3, u16* d3, int n3,
    const float* s4, u16* d4, int n4)
{
  int tid = blockIdx.x * blockDim.x + threadIdx.x;
  int stride = gridDim.x * blockDim.x;
  cast_seg(s0, d0, n0, tid, stride);
  cast_seg(s1, d1, n1, tid, stride);
  cast_seg(s2, d2, n2, tid, stride);
  cast_seg(s3, d3, n3, tid, stride);
  cast_seg(s4, d4, n4, tid, stride);
}

__device__ __forceinline__ void store_val(float* p, float v){ *p = v; }
__device__ __forceinline__ void store_val(u16* p, float v){ *p = f2bf(v); }

// ---------------- 128x128 GEMM  C[M,N] = A[M,K] @ B[N,K]^T + bias ----------------
template<typename OutT, bool RELU>
__global__ __launch_bounds__(256) void gemm_bt(
    const u16* __restrict__ A, const u16* __restrict__ B,
    const float* __restrict__ bias, OutT* __restrict__ C,
    int M, int N, int K)
{
  __shared__ __align__(16) u16 a_lds[2][128*32];
  __shared__ __align__(16) u16 b_lds[2][128*32];
  const int t = threadIdx.x, w = t >> 6, l = t & 63;
  int nwg = gridDim.x * gridDim.y;
  int wg  = blockIdx.y * gridDim.x + blockIdx.x;
  int cpx = nwg >> 3;
  int swz = (wg & 7) * cpx + (wg >> 3);
  const int m0 = (swz / gridDim.x) * 128, n0 = (swz % gridDim.x) * 128;
  const int wr = (w >> 1) * 64, wc = (w & 1) * 64;

  auto stage = [&](int buf, int kt){
    const int k0 = kt * 32;
    #pragma unroll
    for (int i = 0; i < 2; ++i){
      int s = w * 2 + i;
      const u16* ga = A + (size_t)(m0 + s*16 + (l>>2)) * K + k0 + (l&3)*8;
      GLD16(ga, &a_lds[buf][s*512]);
      const u16* gb = B + (size_t)(n0 + s*16 + (l>>2)) * K + k0 + (l&3)*8;
      GLD16(gb, &b_lds[buf][s*512]);
    }
  };

  f32x4 acc[4][4];
  #pragma unroll
  for (int m=0;m<4;++m)
    #pragma unroll
    for (int n=0;n<4;++n) acc[m][n] = (f32x4){0.f,0.f,0.f,0.f};

  stage(0, 0);
  __syncthreads();
  const int nk = K / 32;
  int cur = 0;
  for (int kt = 0; kt < nk; ++kt){
    if (kt + 1 < nk) stage(cur ^ 1, kt + 1);
    short8 af[4], bfr[4];
    #pragma unroll
    for (int m=0;m<4;++m)
      af[m] = *(const short8*)&a_lds[cur][(wr + m*16 + (l&15))*32 + (l>>4)*8];
    #pragma unroll
    for (int n=0;n<4;++n)
      bfr[n] = *(const short8*)&b_lds[cur][(wc + n*16 + (l&15))*32 + (l>>4)*8];
    #pragma unroll
    for (int m=0;m<4;++m)
      #pragma unroll
      for (int n=0;n<4;++n)
        acc[m][n] = __builtin_amdgcn_mfma_f32_16x16x32_bf16(af[m], bfr[n], acc[m][n], 0, 0, 0);
    __syncthreads();
    cur ^= 1;
  }

  #pragma unroll
  for (int n=0;n<4;++n){
    int c = n0 + wc + n*16 + (l & 15);
    float bv = bias ? bias[c] : 0.f;
    #pragma unroll
    for (int m=0;m<4;++m){
      int rbase = m0 + wr + m*16 + (l >> 4) * 4;
      #pragma unroll
      for (int j=0;j<4;++j){
        float v = acc[m][n][j] + bv;
        if (RELU) v = fmaxf(v, 0.f);
        store_val(&C[(size_t)(rbase + j) * N + c], v);
      }
    }
  }
}

// ---------------- fused attention (unchanged from round 4) ----------------
__global__ __launch_bounds__(256) void attn_fused(
    const u16* __restrict__ qkv, float* __restrict__ attn,
    const float* __restrict__ head_mask, u16* __restrict__ attn_out)
{
  __shared__ __align__(16) u16 qs[64*64];
  __shared__ __align__(16) u16 ks[2][64*64];
  __shared__ __align__(16) u16 vt[64*72];
  __shared__ __align__(16) u16 pl[64*72];
  const int t = threadIdx.x, w = t >> 6, l = t & 63;
  const int bh = blockIdx.y, b = bh >> 4, h = bh & 15;
  const int q0 = blockIdx.x * 64;
  const size_t qbase = (size_t)b * 1024 * 3072;
  const float hm = head_mask[0];

  auto stageQ = [&](){
    #pragma unroll
    for (int i=0;i<2;++i){
      int s = w*2 + i;
      int row = s*8 + (l>>3);
      int gcol = (8*(l&7) - 16*(row&3)) & 63;
      const u16* g = qkv + qbase + (size_t)(q0 + row) * 3072 + h*64 + gcol;
      GLD16(g, &qs[s*512]);
    }
  };
  auto stageK = [&](int buf, int ct){
    #pragma unroll
    for (int i=0;i<2;++i){
      int s = w*2 + i;
      int row = s*8 + (l>>3);
      int gcol = (8*(l&7) - 16*(row&3)) & 63;
      const u16* g = qkv + qbase + (size_t)(ct*64 + row) * 3072 + 1024 + h*64 + gcol;
      GLD16(g, &ks[buf][s*512]);
    }
  };

  stageQ();
  stageK(0, 0);
  __syncthreads();

  const int rq = w*16 + (l&15);
  const int qrot = 16*(rq&3);
  short8 a0 = *(const short8*)&qs[rq*64 + (((l>>4)*8      + qrot) & 63)];
  short8 a1 = *(const short8*)&qs[rq*64 + (((l>>4)*8 + 32 + qrot) & 63)];

  auto qkmma = [&](int buf, f32x4* acc){
    #pragma unroll
    for (int n=0;n<4;++n){
      int r = n*16 + (l&15);
      int rot = 16*(r&3);
      short8 b0 = *(const short8*)&ks[buf][r*64 + (((l>>4)*8      + rot) & 63)];
      acc[n] = __builtin_amdgcn_mfma_f32_16x16x32_bf16(a0, b0, acc[n], 0, 0, 0);
    }
    #pragma unroll
    for (int n=0;n<4;++n){
      int r = n*16 + (l&15);
      int rot = 16*(r&3);
      short8 b1 = *(const short8*)&ks[buf][r*64 + (((l>>4)*8 + 32 + rot) & 63)];
      acc[n] = __builtin_amdgcn_mfma_f32_16x16x32_bf16(a1, b1, acc[n], 0, 0, 0);
    }
  };

  // pass 1: per-lane deferred (m,l)
  float m_run[4] = {-1e30f,-1e30f,-1e30f,-1e30f};
  float l_run[4] = {0.f,0.f,0.f,0.f};
  int cur = 0;
  for (int ct = 0; ct < 16; ++ct){
    if (ct < 15) stageK(cur ^ 1, ct + 1);
    f32x4 acc[4];
    #pragma unroll
    for (int n=0;n<4;++n) acc[n] = (f32x4){0.f,0.f,0.f,0.f};
    qkmma(cur, acc);
    #pragma unroll
    for (int j=0;j<4;++j){
      float s0 = acc[0][j]*0.125f, s1 = acc[1][j]*0.125f;
      float s2 = acc[2][j]*0.125f, s3 = acc[3][j]*0.125f;
      float mx = fmaxf(fmaxf(s0,s1), fmaxf(s2,s3));
      float mn = fmaxf(m_run[j], mx);
      l_run[j] = l_run[j] * __expf(m_run[j] - mn)
               + __expf(s0-mn) + __expf(s1-mn) + __expf(s2-mn) + __expf(s3-mn);
      m_run[j] = mn;
    }
    __syncthreads();
    cur ^= 1;
  }

  float rcp[4];
  #pragma unroll
  for (int j=0;j<4;++j){
    float m = m_run[j], lv = l_run[j];
    #pragma unroll
    for (int o=1;o<16;o<<=1){
      float m2 = __shfl_xor(m, o);
      float l2 = __shfl_xor(lv, o);
      float mn = fmaxf(m, m2);
      lv = lv * __expf(m - mn) + l2 * __expf(m2 - mn);
      m = mn;
    }
    m_run[j] = m;
    rcp[j] = hm / lv;
  }

  // pass 2
  float* attn_b = attn + (size_t)bh * 1024 * 1024;
  const int kv = t & 31, u = t >> 5;
  f32x4 accO[4];
  #pragma unroll
  for (int n=0;n<4;++n) accO[n] = (f32x4){0.f,0.f,0.f,0.f};

  stageK(0, 0);
  for (int ct = 0; ct < 16; ++ct){
    const u16* g0 = qkv + qbase + (size_t)(ct*64 + 2*kv) * 3072 + 2048 + h*64 + u*8;
    short8 v0 = *(const short8*)g0;
    short8 v1 = *(const short8*)(g0 + 3072);

    __syncthreads();
    if (ct < 15) stageK(cur ^ 1, ct + 1);

    f32x4 acc2[4];
    #pragma unroll
    for (int n=0;n<4;++n) acc2[n] = (f32x4){0.f,0.f,0.f,0.f};
    qkmma(cur, acc2);

    #pragma unroll
    for (int j=0;j<4;++j){
      int rloc = w*16 + (l>>4)*4 + j;
      float p0 = __expf(acc2[0][j]*0.125f - m_run[j]) * rcp[j];
      float p1 = __expf(acc2[1][j]*0.125f - m_run[j]) * rcp[j];
      float p2 = __expf(acc2[2][j]*0.125f - m_run[j]) * rcp[j];
      float p3 = __expf(acc2[3][j]*0.125f - m_run[j]) * rcp[j];
      float* ap = attn_b + (size_t)(q0 + rloc) * 1024 + ct*64 + (l&15);
      ap[0] = p0; ap[16] = p1; ap[32] = p2; ap[48] = p3;
      u16* pp = &pl[rloc*72 + (l&15)];
      pp[0] = f2bf(p0); pp[16] = f2bf(p1); pp[32] = f2bf(p2); pp[48] = f2bf(p3);
    }
    #pragma unroll
    for (int i=0;i<8;++i){
      unsigned wrd = (unsigned)(u16)v0[i] | ((unsigned)(u16)v1[i] << 16);
      *(unsigned*)&vt[(u*8 + i)*72 + 2*kv] = wrd;
    }
    __syncthreads();
    #pragma unroll
    for (int kk=0;kk<2;++kk){
      short8 pa = *(const short8*)&pl[(w*16 + (l&15))*72 + kk*32 + (l>>4)*8];
      #pragma unroll
      for (int n=0;n<4;++n){
        short8 vf = *(const short8*)&vt[(n*16 + (l&15))*72 + kk*32 + (l>>4)*8];
        accO[n] = __builtin_amdgcn_mfma_f32_16x16x32_bf16(pa, vf, accO[n], 0, 0, 0);
      }
    }
    cur ^= 1;
  }

  #pragma unroll
  for (int n=0;n<4;++n){
    int col = h*64 + n*16 + (l & 15);
    #pragma unroll
    for (int j=0;j<4;++j){
      int row = q0 + w*16 + (l>>4)*4 + j;
      attn_out[(size_t)(b*1024 + row) * 1024 + col] = f2bf(accO[n][j]);
    }
  }
}

// ---------------- wave-per-row residual + LayerNorm (barrier-free) ----------------
// a: bf16 [rows,1024]; r: residual (bf16 if RBF else fp32);
// WF32: write fp32 out; else write bf16 out.
template<bool RBF, bool WF32>
__global__ __launch_bounds__(256) void ln4(
    const u16* __restrict__ a, const void* __restrict__ rp_,
    const float* __restrict__ w, const float* __restrict__ bb,
    float* __restrict__ outf, u16* __restrict__ outb)
{
  const int wv = threadIdx.x >> 6, l = threadIdx.x & 63;
  const int row = blockIdx.x * 4 + wv;
  const size_t base = (size_t)row * 1024 + l * 16;

  short8 a0 = *(const short8*)(a + base);
  short8 a1 = *(const short8*)(a + base + 8);
  float v[16];
  if (RBF){
    const u16* r = (const u16*)rp_;
    short8 r0 = *(const short8*)(r + base);
    short8 r1 = *(const short8*)(r + base + 8);
    #pragma unroll
    for (int i=0;i<8;++i){
      v[i]   = bf2f((u16)a0[i]) + bf2f((u16)r0[i]);
      v[8+i] = bf2f((u16)a1[i]) + bf2f((u16)r1[i]);
    }
  } else {
    const float* r = (const float*)rp_;
    f32x4 r0 = *(const f32x4*)(r + base);
    f32x4 r1 = *(const f32x4*)(r + base + 4);
    f32x4 r2 = *(const f32x4*)(r + base + 8);
    f32x4 r3 = *(const f32x4*)(r + base + 12);
    #pragma unroll
    for (int i=0;i<4;++i){
      v[i]    = bf2f((u16)a0[i])   + r0[i];
      v[4+i]  = bf2f((u16)a0[4+i]) + r1[i];
      v[8+i]  = bf2f((u16)a1[i])   + r2[i];
      v[12+i] = bf2f((u16)a1[4+i]) + r3[i];
    }
  }

  float s1 = 0.f, s2 = 0.f;
  #pragma unroll
  for (int i=0;i<16;++i){ s1 += v[i]; s2 += v[i]*v[i]; }
  #pragma unroll
  for (int o=1;o<64;o<<=1){ s1 += __shfl_xor(s1, o); s2 += __shfl_xor(s2, o); }
  float mu  = s1 * (1.f/1024.f);
  float var = s2 * (1.f/1024.f) - mu*mu;
  float rstd = rsqrtf(var + 1e-5f);

  const int c0 = l * 16;
  float y[16];
  #pragma unroll
  for (int i=0;i<4;++i){
    f32x4 wv4 = *(const f32x4*)(w  + c0 + i*4);
    f32x4 bv4 = *(const f32x4*)(bb + c0 + i*4);
    #pragma unroll
    for (int j=0;j<4;++j) y[i*4+j] = (v[i*4+j]-mu)*rstd*wv4[j] + bv4[j];
  }
  if (WF32){
    #pragma unroll
    for (int i=0;i<4;++i){
      f32x4 o4; o4[0]=y[i*4]; o4[1]=y[i*4+1]; o4[2]=y[i*4+2]; o4[3]=y[i*4+3];
      *(f32x4*)(outf + base + i*4) = o4;
    }
  } else {
    short8 o0, o1;
    #pragma unroll
    for (int i=0;i<8;++i){ o0[i] = f2bf(y[i]); o1[i] = f2bf(y[8+i]); }
    *(short8*)(outb + base)     = o0;
    *(short8*)(outb + base + 8) = o1;
  }
}

// ---------------- launch ----------------
extern "C" void kernel_launch(void* const* d_in, const int* in_sizes, int n_in,
                              void* d_out, int out_size, void* d_ws, size_t ws_size,
                              hipStream_t stream)
{
  const float* x          = (const float*)d_in[0];
  const float* in_proj_w  = (const float*)d_in[1];
  const float* in_proj_b  = (const float*)d_in[2];
  const float* out_proj_w = (const float*)d_in[3];
  const float* out_proj_b = (const float*)d_in[4];
  const float* ln1_w = (const float*)d_in[5];
  const float* ln1_b = (const float*)d_in[6];
  const float* ln2_w = (const float*)d_in[7];
  const float* ln2_b = (const float*)d_in[8];
  const float* ffn_w1 = (const float*)d_in[9];
  const float* ffn_b1 = (const float*)d_in[10];
  const float* ffn_w2 = (const float*)d_in[11];
  const float* ffn_b2 = (const float*)d_in[12];
  const float* head_mask = (const float*)d_in[13];

  const int D = 1024, DFF = 4096;
  const int M = 8192;

  char* ws = (char*)d_ws;
  u16* qkv_bf  = (u16*)ws;                               // [0, 48 MiB)
  char* r1 = ws + 50331648;
  u16* x_bf    = (u16*)r1;                               // 16 MiB
  u16* wqkv_bf = (u16*)(r1 + 16777216);                  // 6 MiB
  u16* wout_bf = (u16*)(r1 + 23068672);                  // 2 MiB
  u16* w1_bf   = (u16*)(r1 + 25165824);                  // 8 MiB
  u16* w2_bf   = (u16*)(r1 + 33554432);                  // 8 MiB
  char* p2 = r1 + 41943040;
  u16* attn_out_bf = (u16*)p2;                           // 16 MiB
  u16* x1_bf = attn_out_bf;                              // alias (after out_proj reads it)
  u16* proj_bf = (u16*)(p2 + 16777216);                  // 16 MiB
  u16* ff_bf = proj_bf;                                  // alias (after ln1 reads it)
  u16* h_bf = (u16*)ws;                                  // 64 MiB, reuses dead qkv_bf + x_bf

  float* out  = (float*)d_out;
  float* attn = out + 8388608;

  cast_all<<<2048, 256, 0, stream>>>(
      x, x_bf, 1048576,
      in_proj_w, wqkv_bf, 393216,
      out_proj_w, wout_bf, 131072,
      ffn_w1, w1_bf, 524288,
      ffn_w2, w2_bf, 524288);

  gemm_bt<u16,false><<<dim3(3*D/128, M/128), 256, 0, stream>>>(x_bf, wqkv_bf, in_proj_b, qkv_bf, M, 3*D, D);
  attn_fused<<<dim3(16, 128), 256, 0, stream>>>(qkv_bf, attn, head_mask, attn_out_bf);
  gemm_bt<u16,false><<<dim3(D/128, M/128), 256, 0, stream>>>(attn_out_bf, wout_bf, out_proj_b, proj_bf, M, D, D);
  ln4<false,false><<<M/4, 256, 0, stream>>>(proj_bf, x, ln1_w, ln1_b, nullptr, x1_bf);
  gemm_bt<u16,true><<<dim3(DFF/128, M/128), 256, 0, stream>>>(x1_bf, w1_bf, ffn_b1, h_bf, M, DFF, D);
  gemm_bt<u16,false><<<dim3(D/128, M/128), 256, 0, stream>>>(h_bf, w2_bf, ffn_b2, ff_bf, M, D, DFF);
  ln4<true,true><<<M/4, 256, 0, stream>>>(ff_bf, x1_bf, ln2_w, ln2_b, out, nullptr);
}

// Round 6
// 589.879 us; speedup vs baseline: 1.1376x; 1.0059x over previous
//
#include <hip/hip_runtime.h>

typedef unsigned short u16;
typedef __attribute__((ext_vector_type(8))) short short8;
typedef __attribute__((ext_vector_type(4))) float f32x4;
typedef __attribute__((ext_vector_type(2))) unsigned uint2v;

__device__ __forceinline__ u16 f2bf(float f){
  unsigned u = __builtin_bit_cast(unsigned, f);
  u += 0x7fffu + ((u >> 16) & 1u);
  return (u16)(u >> 16);
}
__device__ __forceinline__ float bf2f(u16 v){
  unsigned u = (unsigned)v << 16;
  return __builtin_bit_cast(float, u);
}
__device__ __forceinline__ float exp2_fast(float x){
  float r; asm("v_exp_f32 %0, %1" : "=v"(r) : "v"(x)); return r;
}
__device__ __forceinline__ unsigned cvt_pk_bf16(float lo, float hi){
  unsigned r; asm("v_cvt_pk_bf16_f32 %0, %1, %2" : "=v"(r) : "v"(lo), "v"(hi));
  return r;
}

#define GLD16(gp, lp) __builtin_amdgcn_global_load_lds(                         \
    (const __attribute__((address_space(1))) void*)(gp),                        \
    (__attribute__((address_space(3))) void*)(lp), 16, 0, 0)

// ---------------- fused cast: all fp32->bf16 conversions in one kernel ----------------
__device__ __forceinline__ void cast_seg(const float* __restrict__ s,
                                         u16* __restrict__ d, int n8,
                                         int tid, int stride){
  for (int i = tid; i < n8; i += stride){
    const f32x4* p = (const f32x4*)s + (size_t)i * 2;
    f32x4 a = p[0], b = p[1];
    short8 o;
    o[0]=f2bf(a[0]); o[1]=f2bf(a[1]); o[2]=f2bf(a[2]); o[3]=f2bf(a[3]);
    o[4]=f2bf(b[0]); o[5]=f2bf(b[1]); o[6]=f2bf(b[2]); o[7]=f2bf(b[3]);
    *(short8*)(d + (size_t)i * 8) = o;
  }
}

__global__ __launch_bounds__(256) void cast_all(
    const float* s0, u16* d0, int n0,
    const float* s1, u16* d1, int n1,
    const float* s2, u16* d2, int n2,
    const float* s3, u16* d3, int n3,
    const float* s4, u16* d4, int n4)
{
  int tid = blockIdx.x * blockDim.x + threadIdx.x;
  int stride = gridDim.x * blockDim.x;
  cast_seg(s0, d0, n0, tid, stride);
  cast_seg(s1, d1, n1, tid, stride);
  cast_seg(s2, d2, n2, tid, stride);
  cast_seg(s3, d3, n3, tid, stride);
  cast_seg(s4, d4, n4, tid, stride);
}

__device__ __forceinline__ void store_val(float* p, float v){ *p = v; }
__device__ __forceinline__ void store_val(u16* p, float v){ *p = f2bf(v); }

// ---------------- 128x128 GEMM  C[M,N] = A[M,K] @ B[N,K]^T + bias ----------------
template<typename OutT, bool RELU>
__global__ __launch_bounds__(256) void gemm_bt(
    const u16* __restrict__ A, const u16* __restrict__ B,
    const float* __restrict__ bias, OutT* __restrict__ C,
    int M, int N, int K)
{
  __shared__ __align__(16) u16 a_lds[2][128*32];
  __shared__ __align__(16) u16 b_lds[2][128*32];
  const int t = threadIdx.x, w = t >> 6, l = t & 63;
  int nwg = gridDim.x * gridDim.y;
  int wg  = blockIdx.y * gridDim.x + blockIdx.x;
  int cpx = nwg >> 3;
  int swz = (wg & 7) * cpx + (wg >> 3);
  const int m0 = (swz / gridDim.x) * 128, n0 = (swz % gridDim.x) * 128;
  const int wr = (w >> 1) * 64, wc = (w & 1) * 64;

  auto stage = [&](int buf, int kt){
    const int k0 = kt * 32;
    #pragma unroll
    for (int i = 0; i < 2; ++i){
      int s = w * 2 + i;
      const u16* ga = A + (size_t)(m0 + s*16 + (l>>2)) * K + k0 + (l&3)*8;
      GLD16(ga, &a_lds[buf][s*512]);
      const u16* gb = B + (size_t)(n0 + s*16 + (l>>2)) * K + k0 + (l&3)*8;
      GLD16(gb, &b_lds[buf][s*512]);
    }
  };

  f32x4 acc[4][4];
  #pragma unroll
  for (int m=0;m<4;++m)
    #pragma unroll
    for (int n=0;n<4;++n) acc[m][n] = (f32x4){0.f,0.f,0.f,0.f};

  stage(0, 0);
  __syncthreads();
  const int nk = K / 32;
  int cur = 0;
  for (int kt = 0; kt < nk; ++kt){
    if (kt + 1 < nk) stage(cur ^ 1, kt + 1);
    short8 af[4], bfr[4];
    #pragma unroll
    for (int m=0;m<4;++m)
      af[m] = *(const short8*)&a_lds[cur][(wr + m*16 + (l&15))*32 + (l>>4)*8];
    #pragma unroll
    for (int n=0;n<4;++n)
      bfr[n] = *(const short8*)&b_lds[cur][(wc + n*16 + (l&15))*32 + (l>>4)*8];
    #pragma unroll
    for (int m=0;m<4;++m)
      #pragma unroll
      for (int n=0;n<4;++n)
        acc[m][n] = __builtin_amdgcn_mfma_f32_16x16x32_bf16(af[m], bfr[n], acc[m][n], 0, 0, 0);
    __syncthreads();
    cur ^= 1;
  }

  #pragma unroll
  for (int n=0;n<4;++n){
    int c = n0 + wc + n*16 + (l & 15);
    float bv = bias ? bias[c] : 0.f;
    #pragma unroll
    for (int m=0;m<4;++m){
      int rbase = m0 + wr + m*16 + (l >> 4) * 4;
      #pragma unroll
      for (int j=0;j<4;++j){
        float v = acc[m][n][j] + bv;
        if (RELU) v = fmaxf(v, 0.f);
        store_val(&C[(size_t)(rbase + j) * N + c], v);
      }
    }
  }
}

// ---------------- fused attention (swapped-QK layout) ----------------
// mfma(K,Q): D col = q-row (l&15), D rows = key pos. Per lane, per ct-tile:
// 16 scores of ONE q-row at s = n*16 + 4*(l>>4) + j (j contiguous in acc[n]).
// Pass 1: per-lane scalar (m,l), 2-round combine over lanes l^16/l^32.
// Pass 2: recompute (bitwise-identical), f32x4 attn stores, cvt_pk+b64 P repack,
// PV MFMA unchanged.
__global__ __launch_bounds__(256) void attn_fused(
    const u16* __restrict__ qkv, float* __restrict__ attn,
    const float* __restrict__ head_mask, u16* __restrict__ attn_out)
{
  __shared__ __align__(16) u16 qs[64*64];
  __shared__ __align__(16) u16 ks[2][64*64];
  __shared__ __align__(16) u16 vt[64*72];
  __shared__ __align__(16) u16 pl[64*72];
  const int t = threadIdx.x, w = t >> 6, l = t & 63;
  const int bh = blockIdx.y, b = bh >> 4, h = bh & 15;
  const int q0 = blockIdx.x * 64;
  const size_t qbase = (size_t)b * 1024 * 3072;
  const float hm = head_mask[0];
  const float SC = 0.125f * 1.44269504f;   // log2(e)/8; softmax in exp2 domain

  auto stageQ = [&](){
    #pragma unroll
    for (int i=0;i<2;++i){
      int s = w*2 + i;
      int row = s*8 + (l>>3);
      int gcol = (8*(l&7) - 16*(row&3)) & 63;
      const u16* g = qkv + qbase + (size_t)(q0 + row) * 3072 + h*64 + gcol;
      GLD16(g, &qs[s*512]);
    }
  };
  auto stageK = [&](int buf, int ct){
    #pragma unroll
    for (int i=0;i<2;++i){
      int s = w*2 + i;
      int row = s*8 + (l>>3);
      int gcol = (8*(l&7) - 16*(row&3)) & 63;
      const u16* g = qkv + qbase + (size_t)(ct*64 + row) * 3072 + 1024 + h*64 + gcol;
      GLD16(g, &ks[buf][s*512]);
    }
  };

  stageQ();
  stageK(0, 0);
  __syncthreads();

  // Q fragments (B-operand now): rows w*16+(l&15), d-halves
  const int rq = w*16 + (l&15);
  const int qrot = 16*(rq&3);
  short8 a0 = *(const short8*)&qs[rq*64 + (((l>>4)*8      + qrot) & 63)];
  short8 a1 = *(const short8*)&qs[rq*64 + (((l>>4)*8 + 32 + qrot) & 63)];

  // swapped: mfma(kfrag, qfrag, acc)
  auto qkmma = [&](int buf, f32x4* acc){
    #pragma unroll
    for (int n=0;n<4;++n){
      int r = n*16 + (l&15);
      int rot = 16*(r&3);
      short8 b0 = *(const short8*)&ks[buf][r*64 + (((l>>4)*8      + rot) & 63)];
      acc[n] = __builtin_amdgcn_mfma_f32_16x16x32_bf16(b0, a0, acc[n], 0, 0, 0);
    }
    #pragma unroll
    for (int n=0;n<4;++n){
      int r = n*16 + (l&15);
      int rot = 16*(r&3);
      short8 b1 = *(const short8*)&ks[buf][r*64 + (((l>>4)*8 + 32 + rot) & 63)];
      acc[n] = __builtin_amdgcn_mfma_f32_16x16x32_bf16(b1, a1, acc[n], 0, 0, 0);
    }
  };

  // ---- pass 1: per-lane scalar deferred (m,l) in exp2 domain ----
  float m_run = -1e30f, l_run = 0.f;
  int cur = 0;
  for (int ct = 0; ct < 16; ++ct){
    if (ct < 15) stageK(cur ^ 1, ct + 1);
    f32x4 acc[4];
    #pragma unroll
    for (int n=0;n<4;++n) acc[n] = (f32x4){0.f,0.f,0.f,0.f};
    qkmma(cur, acc);
    float s[16];
    #pragma unroll
    for (int n=0;n<4;++n)
      #pragma unroll
      for (int j=0;j<4;++j) s[n*4+j] = acc[n][j] * SC;
    float mx = s[0];
    #pragma unroll
    for (int i=1;i<16;++i) mx = fmaxf(mx, s[i]);
    float mn = fmaxf(m_run, mx);
    float es = 0.f;
    #pragma unroll
    for (int i=0;i<16;++i) es += exp2_fast(s[i] - mn);
    l_run = l_run * exp2_fast(m_run - mn) + es;
    m_run = mn;
    __syncthreads();
    cur ^= 1;
  }

  // combine over the 4 lanes sharing a q-row (l ^ 16, l ^ 32)
  #pragma unroll
  for (int o=16;o<64;o<<=1){
    float m2 = __shfl_xor(m_run, o);
    float l2 = __shfl_xor(l_run, o);
    float mn = fmaxf(m_run, m2);
    l_run = l_run * exp2_fast(m_run - mn) + l2 * exp2_fast(m2 - mn);
    m_run = mn;
  }
  const float rcp = hm / l_run;

  // ---- pass 2: recompute, normalize, vector stores, PV ----
  float* attn_b = attn + (size_t)bh * 1024 * 1024;
  const int kv = t & 31, u = t >> 5;
  f32x4 accO[4];
  #pragma unroll
  for (int n=0;n<4;++n) accO[n] = (f32x4){0.f,0.f,0.f,0.f};

  const int qrow = w*16 + (l&15);          // this lane's q-row (local)
  const int scol0 = 4*(l>>4);              // s-offset within each 16-group
  stageK(0, 0);
  for (int ct = 0; ct < 16; ++ct){
    const u16* g0 = qkv + qbase + (size_t)(ct*64 + 2*kv) * 3072 + 2048 + h*64 + u*8;
    short8 v0 = *(const short8*)g0;
    short8 v1 = *(const short8*)(g0 + 3072);

    __syncthreads();
    if (ct < 15) stageK(cur ^ 1, ct + 1);

    f32x4 acc2[4];
    #pragma unroll
    for (int n=0;n<4;++n) acc2[n] = (f32x4){0.f,0.f,0.f,0.f};
    qkmma(cur, acc2);

    #pragma unroll
    for (int n=0;n<4;++n){
      f32x4 p;
      #pragma unroll
      for (int j=0;j<4;++j) p[j] = exp2_fast(acc2[n][j]*SC - m_run) * rcp;
      *(f32x4*)(attn_b + (size_t)(q0 + qrow)*1024 + ct*64 + n*16 + scol0) = p;
      uint2v pk;
      pk[0] = cvt_pk_bf16(p[0], p[1]);
      pk[1] = cvt_pk_bf16(p[2], p[3]);
      *(uint2v*)&pl[qrow*72 + n*16 + scol0] = pk;
    }
    #pragma unroll
    for (int i=0;i<8;++i){
      unsigned wrd = (unsigned)(u16)v0[i] | ((unsigned)(u16)v1[i] << 16);
      *(unsigned*)&vt[(u*8 + i)*72 + 2*kv] = wrd;
    }
    __syncthreads();
    #pragma unroll
    for (int kk=0;kk<2;++kk){
      short8 pa = *(const short8*)&pl[(w*16 + (l&15))*72 + kk*32 + (l>>4)*8];
      #pragma unroll
      for (int n=0;n<4;++n){
        short8 vf = *(const short8*)&vt[(n*16 + (l&15))*72 + kk*32 + (l>>4)*8];
        accO[n] = __builtin_amdgcn_mfma_f32_16x16x32_bf16(pa, vf, accO[n], 0, 0, 0);
      }
    }
    cur ^= 1;
  }

  #pragma unroll
  for (int n=0;n<4;++n){
    int col = h*64 + n*16 + (l & 15);
    #pragma unroll
    for (int j=0;j<4;++j){
      int row = q0 + w*16 + (l>>4)*4 + j;
      attn_out[(size_t)(b*1024 + row) * 1024 + col] = f2bf(accO[n][j]);
    }
  }
}

// ---------------- wave-per-row residual + LayerNorm (barrier-free) ----------------
template<bool RBF, bool WF32>
__global__ __launch_bounds__(256) void ln4(
    const u16* __restrict__ a, const void* __restrict__ rp_,
    const float* __restrict__ w, const float* __restrict__ bb,
    float* __restrict__ outf, u16* __restrict__ outb)
{
  const int wv = threadIdx.x >> 6, l = threadIdx.x & 63;
  const int row = blockIdx.x * 4 + wv;
  const size_t base = (size_t)row * 1024 + l * 16;

  short8 a0 = *(const short8*)(a + base);
  short8 a1 = *(const short8*)(a + base + 8);
  float v[16];
  if (RBF){
    const u16* r = (const u16*)rp_;
    short8 r0 = *(const short8*)(r + base);
    short8 r1 = *(const short8*)(r + base + 8);
    #pragma unroll
    for (int i=0;i<8;++i){
      v[i]   = bf2f((u16)a0[i]) + bf2f((u16)r0[i]);
      v[8+i] = bf2f((u16)a1[i]) + bf2f((u16)r1[i]);
    }
  } else {
    const float* r = (const float*)rp_;
    f32x4 r0 = *(const f32x4*)(r + base);
    f32x4 r1 = *(const f32x4*)(r + base + 4);
    f32x4 r2 = *(const f32x4*)(r + base + 8);
    f32x4 r3 = *(const f32x4*)(r + base + 12);
    #pragma unroll
    for (int i=0;i<4;++i){
      v[i]    = bf2f((u16)a0[i])   + r0[i];
      v[4+i]  = bf2f((u16)a0[4+i]) + r1[i];
      v[8+i]  = bf2f((u16)a1[i])   + r2[i];
      v[12+i] = bf2f((u16)a1[4+i]) + r3[i];
    }
  }

  float s1 = 0.f, s2 = 0.f;
  #pragma unroll
  for (int i=0;i<16;++i){ s1 += v[i]; s2 += v[i]*v[i]; }
  #pragma unroll
  for (int o=1;o<64;o<<=1){ s1 += __shfl_xor(s1, o); s2 += __shfl_xor(s2, o); }
  float mu  = s1 * (1.f/1024.f);
  float var = s2 * (1.f/1024.f) - mu*mu;
  float rstd = rsqrtf(var + 1e-5f);

  const int c0 = l * 16;
  float y[16];
  #pragma unroll
  for (int i=0;i<4;++i){
    f32x4 wv4 = *(const f32x4*)(w  + c0 + i*4);
    f32x4 bv4 = *(const f32x4*)(bb + c0 + i*4);
    #pragma unroll
    for (int j=0;j<4;++j) y[i*4+j] = (v[i*4+j]-mu)*rstd*wv4[j] + bv4[j];
  }
  if (WF32){
    #pragma unroll
    for (int i=0;i<4;++i){
      f32x4 o4; o4[0]=y[i*4]; o4[1]=y[i*4+1]; o4[2]=y[i*4+2]; o4[3]=y[i*4+3];
      *(f32x4*)(outf + base + i*4) = o4;
    }
  } else {
    short8 o0, o1;
    #pragma unroll
    for (int i=0;i<8;++i){ o0[i] = f2bf(y[i]); o1[i] = f2bf(y[8+i]); }
    *(short8*)(outb + base)     = o0;
    *(short8*)(outb + base + 8) = o1;
  }
}

// ---------------- launch ----------------
extern "C" void kernel_launch(void* const* d_in, const int* in_sizes, int n_in,
                              void* d_out, int out_size, void* d_ws, size_t ws_size,
                              hipStream_t stream)
{
  const float* x          = (const float*)d_in[0];
  const float* in_proj_w  = (const float*)d_in[1];
  const float* in_proj_b  = (const float*)d_in[2];
  const float* out_proj_w = (const float*)d_in[3];
  const float* out_proj_b = (const float*)d_in[4];
  const float* ln1_w = (const float*)d_in[5];
  const float* ln1_b = (const float*)d_in[6];
  const float* ln2_w = (const float*)d_in[7];
  const float* ln2_b = (const float*)d_in[8];
  const float* ffn_w1 = (const float*)d_in[9];
  const float* ffn_b1 = (const float*)d_in[10];
  const float* ffn_w2 = (const float*)d_in[11];
  const float* ffn_b2 = (const float*)d_in[12];
  const float* head_mask = (const float*)d_in[13];

  const int D = 1024, DFF = 4096;
  const int M = 8192;

  char* ws = (char*)d_ws;
  u16* qkv_bf  = (u16*)ws;                               // [0, 48 MiB)
  char* r1 = ws + 50331648;
  u16* x_bf    = (u16*)r1;                               // 16 MiB
  u16* wqkv_bf = (u16*)(r1 + 16777216);                  // 6 MiB
  u16* wout_bf = (u16*)(r1 + 23068672);                  // 2 MiB
  u16* w1_bf   = (u16*)(r1 + 25165824);                  // 8 MiB
  u16* w2_bf   = (u16*)(r1 + 33554432);                  // 8 MiB
  char* p2 = r1 + 41943040;
  u16* attn_out_bf = (u16*)p2;                           // 16 MiB
  u16* x1_bf = attn_out_bf;                              // alias (after out_proj reads it)
  u16* proj_bf = (u16*)(p2 + 16777216);                  // 16 MiB
  u16* ff_bf = proj_bf;                                  // alias (after ln1 reads it)
  u16* h_bf = (u16*)ws;                                  // 64 MiB, reuses dead qkv_bf + x_bf

  float* out  = (float*)d_out;
  float* attn = out + 8388608;

  cast_all<<<2048, 256, 0, stream>>>(
      x, x_bf, 1048576,
      in_proj_w, wqkv_bf, 393216,
      out_proj_w, wout_bf, 131072,
      ffn_w1, w1_bf, 524288,
      ffn_w2, w2_bf, 524288);

  gemm_bt<u16,false><<<dim3(3*D/128, M/128), 256, 0, stream>>>(x_bf, wqkv_bf, in_proj_b, qkv_bf, M, 3*D, D);
  attn_fused<<<dim3(16, 128), 256, 0, stream>>>(qkv_bf, attn, head_mask, attn_out_bf);
  gemm_bt<u16,false><<<dim3(D/128, M/128), 256, 0, stream>>>(attn_out_bf, wout_bf, out_proj_b, proj_bf, M, D, D);
  ln4<true,false><<<M/4, 256, 0, stream>>>(proj_bf, x_bf, ln1_w, ln1_b, nullptr, x1_bf);
  gemm_bt<u16,true><<<dim3(DFF/128, M/128), 256, 0, stream>>>(x1_bf, w1_bf, ffn_b1, h_bf, M, DFF, D);
  gemm_bt<u16,false><<<dim3(D/128, M/128), 256, 0, stream>>>(h_bf, w2_bf, ffn_b2, ff_bf, M, D, DFF);
  ln4<true,true><<<M/4, 256, 0, stream>>>(ff_bf, x1_bf, ln2_w, ln2_b, out, nullptr);
}